// Round 18
// baseline (585.539 us; speedup 1.0000x reference)
//
#include <hip/hip_runtime.h>
#include <hip/hip_bf16.h>

// ---------- constants ----------
#define B 16
#define C 64
#define H 128
#define W 128
#define S 32
#define S2 1024
#define HW 16384

typedef __attribute__((ext_vector_type(8))) short bf16x8;
typedef __attribute__((ext_vector_type(4))) float f32x4;
typedef __attribute__((ext_vector_type(8))) unsigned short u16x8;
typedef __attribute__((ext_vector_type(4))) unsigned short u16x4;

static __device__ __forceinline__ unsigned short f2bf(float v) {
    __hip_bfloat16 h = __float2bfloat16(v);
    return *reinterpret_cast<unsigned short*>(&h);
}
static __device__ __forceinline__ float bf2f(unsigned short u) {
    union { unsigned int i; float f; } cv;
    cv.i = ((unsigned int)u) << 16;
    return cv.f;
}

// ---------- Keys cubic kernel (a = -0.5) ----------
__device__ __forceinline__ float keys(float t) {
    t = fabsf(t);
    if (t >= 2.f) return 0.f;
    float t2 = t * t, t3 = t2 * t;
    if (t >= 1.f) return -0.5f * t3 + 2.5f * t2 - 4.f * t + 2.f;
    return 1.5f * t3 - 2.5f * t2 + 1.f;
}

// ---------- kernel 0: precompute resize weights ----------
__global__ void k_init(float* __restrict__ wd, float* __restrict__ wu) {
    int tid = threadIdx.x;
    if (tid < 32) {
        int i = tid;
        float sf = 4.f * i + 1.5f;
        int j0 = 4 * i - 6;
        float w[16];
        float s = 0.f;
        for (int k = 0; k < 16; k++) {
            int j = j0 + k;
            float v = 0.f;
            if (j >= 0 && j < 128) v = keys((sf - (float)j) * 0.25f);
            w[k] = v; s += v;
        }
        float inv = 1.f / s;
        for (int k = 0; k < 16; k++) wd[i * 16 + k] = w[k] * inv;
    } else if (tid >= 64 && tid < 192) {
        int i = tid - 64;
        float sf = 0.25f * i - 0.375f;
        int j0 = (int)floorf(sf) - 1;
        float w[4];
        float s = 0.f;
        for (int k = 0; k < 4; k++) {
            int j = j0 + k;
            float v = 0.f;
            if (j >= 0 && j < 32) v = keys(sf - (float)j);
            w[k] = v; s += v;
        }
        float inv = 1.f / s;
        for (int k = 0; k < 4; k++) wu[i * 4 + k] = w[k] * inv;
    }
}

// ---------- kernel 1: bicubic downsample (LDS-staged, conflict-free) ----------
__global__ void __launch_bounds__(256) k_down(const float* __restrict__ x, const float* __restrict__ y,
                                              const float* __restrict__ wd, unsigned short* __restrict__ re) {
    int bid = blockIdx.x;
    int img = bid >> 10;
    int bc = bid & 1023;
    const float* src = (img ? y : x) + (size_t)bc * HW;
    __shared__ unsigned short xsrc[128 * 128];
    __shared__ float tmp[32 * 160];
    __shared__ float wsh[512];
    int tid = threadIdx.x;
    for (int i = tid; i < 512; i += 256) wsh[i] = wd[i];
    #pragma unroll
    for (int it = 0; it < 16; ++it) {
        int i4 = (tid + it * 256) * 4;
        float4 v = *reinterpret_cast<const float4*>(src + i4);
        u16x4 o = {f2bf(v.x), f2bf(v.y), f2bf(v.z), f2bf(v.w)};
        *reinterpret_cast<u16x4*>(&xsrc[i4]) = o;
    }
    __syncthreads();
    #pragma unroll
    for (int it = 0; it < 16; ++it) {
        int idx = tid + it * 256;
        int oy = idx >> 7, xx = idx & 127;
        int j0 = 4 * oy - 6;
        float acc = 0.f;
        #pragma unroll
        for (int k = 0; k < 16; k++) {
            int j = j0 + k;
            if (j >= 0 && j < 128) acc += wsh[oy * 16 + k] * bf2f(xsrc[j * 128 + xx]);
        }
        tmp[oy * 160 + (xx & 3) * 40 + (xx >> 2)] = acc;
    }
    __syncthreads();
    #pragma unroll
    for (int it = 0; it < 4; ++it) {
        int idx = tid + it * 256;
        int oy = idx >> 5, ox = idx & 31;
        int j0 = 4 * ox - 6;
        float acc = 0.f;
        #pragma unroll
        for (int k = 0; k < 16; k++) {
            int j = j0 + k;
            if (j >= 0 && j < 128) acc += wsh[ox * 16 + k] * tmp[oy * 160 + (j & 3) * 40 + (j >> 2)];
        }
        re[(size_t)bid * 1024 + idx] = f2bf(acc);
    }
}

// ---------- weight pack (interleaved k-map) for qkv convs ----------
__global__ void k_wpack(const float* __restrict__ w, const float* __restrict__ s,
                        unsigned short* __restrict__ wpk, int cin) {
    int ks = blockIdx.x;
    int tid = threadIdx.x;
    int lane = tid & 63, ct = tid >> 6;
    int cb = ks / 9, kk = ks % 9;
    int m = ct * 16 + (lane & 15);
    int qq = lane >> 4;
    float sc = s[m];
    u16x8 outv;
    #pragma unroll
    for (int j = 0; j < 8; ++j) {
        int k = qq * 4 + (j & 3) + ((j >> 2) << 4);
        int ci = cb * 32 + k;
        float v = w[((size_t)m * cin + ci) * 9 + kk] * sc;
        outv[j] = f2bf(v);
    }
    *reinterpret_cast<u16x8*>(wpk + ((size_t)(ks * 4 + ct) * 64 + lane) * 8) = outv;
}

// ---------- weight pack (contiguous-8 k-map) for red/sec convs ----------
__global__ void k_wpackc(const float* __restrict__ w, const float* __restrict__ s,
                         unsigned short* __restrict__ wpk, int cin) {
    int ks = blockIdx.x;
    int tid = threadIdx.x;
    int lane = tid & 63, ct = tid >> 6;
    int cb = ks / 9, kk = ks % 9;
    int m = ct * 16 + (lane & 15);
    int qq = (lane >> 4) & 3;
    float sc = s[m];
    u16x8 outv;
    #pragma unroll
    for (int j = 0; j < 8; ++j) {
        int ci = cb * 32 + qq * 8 + j;
        float v = w[((size_t)m * cin + ci) * 9 + kk] * sc;
        outv[j] = f2bf(v);
    }
    *reinterpret_cast<u16x8*>(wpk + ((size_t)(ks * 4 + ct) * 64 + lane) * 8) = outv;
}

// ---------- kernel 2: six QKV 3x3 convs via MFMA, outputs routed per q ----------
struct QkvBias { const float* b[6]; };

__global__ void __launch_bounds__(256) k_qkv2(const unsigned short* __restrict__ re,
                                              const unsigned short* __restrict__ wpkq,
                                              QkvBias bias,
                                              unsigned short* __restrict__ qt,
                                              unsigned short* __restrict__ kt,
                                              unsigned short* __restrict__ vn) {
    int bid = blockIdx.x;                 // q*64 + b*4 + quad
    int q = bid >> 6;
    int rem = bid & 63;
    int b = rem >> 2;
    int quad = rem & 3;
    int img = (q < 3) ? 0 : 1;
    const unsigned short* src = re + ((size_t)(img * 16 + b)) * 64 * 1024;
    const bf16x8* wp = reinterpret_cast<const bf16x8*>(wpkq + (size_t)q * 18 * 4 * 64 * 8);
    const float* bptr = bias.b[q];

    int tid = threadIdx.x;
    int lane = tid & 63, w = tid >> 6;
    int l15 = lane & 15, qg = lane >> 4;

    __shared__ __align__(16) unsigned short xs[10 * 34 * 32];

    if (tid < 160) {
        int r = tid >> 4;
        int inner = tid & 15;
        int col = (inner >> 3) ? 33 : 0;
        int qd = inner & 7;
        int sbase = ((qd & 3) << 3) + ((qd >> 2) << 2);
        int sbs = sbase ^ ((((col >> 1) & 3)) << 3);
        u16x4 z = {0, 0, 0, 0};
        *reinterpret_cast<u16x4*>(&xs[(r * 34 + col) * 32 + sbs]) = z;
    }

    f32x4 acc[4][4] = {};

    for (int cb = 0; cb < 2; ++cb) {
        __syncthreads();
        #pragma unroll
        for (int tt = 0; tt < 2; ++tt) {
            int task = tid + tt * 256;
            if (task < 320) {
                int r = task >> 5;
                int inner = task & 31;
                int qd = inner >> 2, xc = inner & 3;
                int yy = quad * 8 - 1 + r;
                int x0 = xc * 8;
                int ci0 = cb * 32 + qd * 4;
                u16x8 v0, v1, v2, v3;
                if (yy >= 0 && yy < 32) {
                    const unsigned short* sp = src + (size_t)ci0 * 1024 + yy * 32 + x0;
                    v0 = *reinterpret_cast<const u16x8*>(sp);
                    v1 = *reinterpret_cast<const u16x8*>(sp + 1024);
                    v2 = *reinterpret_cast<const u16x8*>(sp + 2048);
                    v3 = *reinterpret_cast<const u16x8*>(sp + 3072);
                } else {
                    v0 = (u16x8)0; v1 = (u16x8)0; v2 = (u16x8)0; v3 = (u16x8)0;
                }
                int sbase = ((qd & 3) << 3) + ((qd >> 2) << 2);
                #pragma unroll
                for (int dx = 0; dx < 8; ++dx) {
                    int col = x0 + 1 + dx;
                    int sbs = sbase ^ (((col >> 1) & 3) << 3);
                    u16x4 pk = {v0[dx], v1[dx], v2[dx], v3[dx]};
                    *reinterpret_cast<u16x4*>(&xs[(r * 34 + col) * 32 + sbs]) = pk;
                }
            }
        }
        __syncthreads();
        #pragma unroll
        for (int ky = 0; ky < 3; ++ky) {
            #pragma unroll
            for (int kx = 0; kx < 3; ++kx) {
                int ksidx = cb * 9 + ky * 3 + kx;
                bf16x8 afr[4];
                #pragma unroll
                for (int ct = 0; ct < 4; ++ct)
                    afr[ct] = wp[((size_t)(ksidx * 4 + ct) << 6) + lane];
                bf16x8 bfr[4];
                #pragma unroll
                for (int nt = 0; nt < 4; ++nt) {
                    int rp = nt >> 1;
                    int col = (nt & 1) * 16 + l15 + kx;
                    int r = w * 2 + rp + ky;
                    int sbs = (qg ^ ((col >> 1) & 3)) << 3;
                    bfr[nt] = *reinterpret_cast<const bf16x8*>(&xs[(r * 34 + col) * 32 + sbs]);
                }
                #pragma unroll
                for (int ct = 0; ct < 4; ++ct)
                    #pragma unroll
                    for (int nt = 0; nt < 4; ++nt)
                        acc[ct][nt] = __builtin_amdgcn_mfma_f32_16x16x32_bf16(afr[ct], bfr[nt], acc[ct][nt], 0, 0, 0);
            }
        }
    }

    // epilogue
    int pair = (q < 3) ? 0 : 1;
    bool isV = (q == 2 || q == 5);
    unsigned short* dst;
    if (q == 0 || q == 3)      dst = qt + ((size_t)(pair * 16 + b)) * 65536;
    else if (q == 1 || q == 4) dst = kt + ((size_t)(pair * 16 + b)) * 65536;
    else                       dst = vn + ((size_t)(pair * 16 + b)) * 65536;
    #pragma unroll
    for (int ct = 0; ct < 4; ++ct) {
        float4 bi = *reinterpret_cast<const float4*>(bptr + ct * 16 + qg * 4);
        #pragma unroll
        for (int nt = 0; nt < 4; ++nt) {
            int pxl = nt * 16 + l15;
            int rowg = quad * 8 + w * 2 + (pxl >> 5);
            int colg = pxl & 31;
            int px = rowg * 32 + colg;
            #pragma unroll
            for (int reg = 0; reg < 4; ++reg) {
                int co = ct * 16 + qg * 4 + reg;
                float bv = (reg == 0) ? bi.x : (reg == 1) ? bi.y : (reg == 2) ? bi.z : bi.w;
                float v = fmaxf(acc[ct][nt][reg] + bv, 0.f);
                unsigned short bf = f2bf(v);
                if (isV) dst[(size_t)co * 1024 + px] = bf;
                else     dst[(size_t)px * 64 + co] = bf;
            }
        }
    }
}

// ---------- pack Q/K (px-major [1024][64]) into MFMA fragment order ----------
__global__ void k_packa(const unsigned short* __restrict__ qt,
                        const unsigned short* __restrict__ kt,
                        unsigned short* __restrict__ qtf,
                        unsigned short* __restrict__ ktf) {
    int bid = blockIdx.x;            // tsel*128 + b*8 + seg
    int tsel = bid >> 7;
    int b = (bid >> 3) & 15;
    int seg = bid & 7;
    int tid = threadIdx.x;
    int lane = tid & 63, w = tid >> 6;
    int l15 = lane & 15, qg = lane >> 4;
    const unsigned short* src = (tsel < 2 ? qt : kt) + ((size_t)((tsel & 1) * 16 + b)) * 65536;
    unsigned short* dst = (tsel < 2 ? qtf : ktf) + ((size_t)((tsel & 1) * 16 + b)) * 65536;
    #pragma unroll
    for (int it = 0; it < 4; ++it) {
        int fi = seg * 16 + it * 4 + w;
        int tf = fi >> 1, kb = fi & 1;
        const unsigned short* row = src + (size_t)(tf * 16 + l15) * 64 + kb * 32 + qg * 4;
        u16x4 a0 = *reinterpret_cast<const u16x4*>(row);
        u16x4 a1 = *reinterpret_cast<const u16x4*>(row + 16);
        u16x8 o;
        #pragma unroll
        for (int j = 0; j < 4; ++j) { o[j] = a0[j]; o[4 + j] = a1[j]; }
        *reinterpret_cast<u16x8*>(dst + (size_t)fi * 512 + lane * 8) = o;
    }
}

// ---------- pack V (co-major [64][1024]) into fragment order; also builds DV=RV+IV ----------
__global__ void k_packv(const unsigned short* __restrict__ vn,
                        unsigned short* __restrict__ vf) {
    int bid = blockIdx.x;            // b*8 + seg
    int b = bid >> 3;
    int seg = bid & 7;
    int tid = threadIdx.x;
    int lane = tid & 63, w = tid >> 6;
    int l15 = lane & 15, qg = lane >> 4;
    const unsigned short* rv = vn + (size_t)b * 65536;
    const unsigned short* iv = vn + (size_t)(16 + b) * 65536;
    #pragma unroll
    for (int it = 0; it < 4; ++it) {
        int fi = seg * 16 + it * 4 + w;
        int cf = fi >> 5, tq = fi & 31;
        int c = cf * 16 + l15;
        size_t roff = (size_t)c * 1024 + tq * 32 + qg * 4;
        u16x4 r0 = *reinterpret_cast<const u16x4*>(rv + roff);
        u16x4 r1 = *reinterpret_cast<const u16x4*>(rv + roff + 16);
        u16x4 i0 = *reinterpret_cast<const u16x4*>(iv + roff);
        u16x4 i1 = *reinterpret_cast<const u16x4*>(iv + roff + 16);
        u16x8 orv, oiv, odv;
        #pragma unroll
        for (int j = 0; j < 4; ++j) {
            orv[j] = r0[j]; orv[4 + j] = r1[j];
            oiv[j] = i0[j]; oiv[4 + j] = i1[j];
            odv[j] = f2bf(bf2f(r0[j]) + bf2f(i0[j]));
            odv[4 + j] = f2bf(bf2f(r1[j]) + bf2f(i1[j]));
        }
        size_t eoff = ((size_t)b * 128 + fi) * 512 + lane * 8;
        *reinterpret_cast<u16x8*>(vf + eoff) = orv;
        *reinterpret_cast<u16x8*>(vf + 1048576 + eoff) = oiv;
        *reinterpret_cast<u16x8*>(vf + 2097152 + eoff) = odv;
    }
}

// ---------- kernel 3: MFMA attention, all operands in fragment layout ----------
__global__ void __launch_bounds__(256) k_attn3(const unsigned short* __restrict__ QTF,
                                               const unsigned short* __restrict__ KTF,
                                               const unsigned short* __restrict__ VF,
                                               float* __restrict__ ref) {
    int bid = blockIdx.x;                  // a*1024 + b*64 + stile
    int a = bid >> 10;
    int b = (bid >> 6) & 15;
    int stile = bid & 63;
    int qsel = (a == 0 || a == 2) ? 0 : 1;
    int ksel = (a == 0 || a == 3) ? 0 : 1;
    int vsel = (a < 2) ? 2 : (a == 2 ? 0 : 1);

    int tid = threadIdx.x;
    int lane = tid & 63, w = tid >> 6;
    int l15 = lane & 15, qg = lane >> 4;

    const bf16x8* qf = reinterpret_cast<const bf16x8*>(QTF) + ((size_t)(qsel * 16 + b) * 128) * 64;
    const bf16x8* kf = reinterpret_cast<const bf16x8*>(KTF) + ((size_t)(ksel * 16 + b) * 128) * 64;
    const bf16x8* vfb = reinterpret_cast<const bf16x8*>(VF) + ((size_t)(vsel * 16 + b) * 128) * 64;

    __shared__ float mxw[4][16];
    __shared__ float smw[4][16];
    __shared__ float rbuf[4][64 * 16];

    bf16x8 bk0 = kf[(size_t)(stile * 2 + 0) * 64 + lane];
    bf16x8 bk1 = kf[(size_t)(stile * 2 + 1) * 64 + lane];
    f32x4 acc[16] = {};
    #pragma unroll
    for (int mf = 0; mf < 16; ++mf) {
        int tf = w * 16 + mf;
        bf16x8 a0 = qf[(size_t)(tf * 2 + 0) * 64 + lane];
        bf16x8 a1 = qf[(size_t)(tf * 2 + 1) * 64 + lane];
        acc[mf] = __builtin_amdgcn_mfma_f32_16x16x32_bf16(a0, bk0, acc[mf], 0, 0, 0);
        acc[mf] = __builtin_amdgcn_mfma_f32_16x16x32_bf16(a1, bk1, acc[mf], 0, 0, 0);
    }

    float mx = -1e30f;
    #pragma unroll
    for (int mf = 0; mf < 16; ++mf)
        #pragma unroll
        for (int r = 0; r < 4; ++r) mx = fmaxf(mx, acc[mf][r]);
    mx = fmaxf(mx, __shfl_xor(mx, 16));
    mx = fmaxf(mx, __shfl_xor(mx, 32));
    if (qg == 0) mxw[w][l15] = mx;
    __syncthreads();
    float M = fmaxf(fmaxf(mxw[0][l15], mxw[1][l15]), fmaxf(mxw[2][l15], mxw[3][l15]));
    float sm = 0.f;
    #pragma unroll
    for (int mf = 0; mf < 16; ++mf)
        #pragma unroll
        for (int r = 0; r < 4; ++r) {
            float e = __builtin_amdgcn_exp2f((acc[mf][r] - M) * 1.4426950408889634f);
            acc[mf][r] = e;
            sm += e;
        }
    sm += __shfl_xor(sm, 16);
    sm += __shfl_xor(sm, 32);
    if (qg == 0) smw[w][l15] = sm;
    __syncthreads();
    float inv = 1.f / (smw[0][l15] + smw[1][l15] + smw[2][l15] + smw[3][l15]);

    f32x4 pacc[4] = {};
    #pragma unroll
    for (int kk = 0; kk < 8; ++kk) {
        bf16x8 bp;
        #pragma unroll
        for (int j = 0; j < 4; ++j) {
            bp[j] = (short)f2bf(acc[2 * kk][j]);
            bp[4 + j] = (short)f2bf(acc[2 * kk + 1][j]);
        }
        #pragma unroll
        for (int cf = 0; cf < 4; ++cf) {
            bf16x8 av = vfb[(size_t)(cf * 32 + w * 8 + kk) * 64 + lane];
            pacc[cf] = __builtin_amdgcn_mfma_f32_16x16x32_bf16(av, bp, pacc[cf], 0, 0, 0);
        }
    }
    #pragma unroll
    for (int cf = 0; cf < 4; ++cf)
        #pragma unroll
        for (int r = 0; r < 4; ++r)
            rbuf[w][(cf * 16 + qg * 4 + r) * 16 + l15] = pacc[cf][r] * inv;
    __syncthreads();

    {
        int c = tid >> 2, sg = tid & 3;
        f32x4 o;
        #pragma unroll
        for (int k2 = 0; k2 < 4; ++k2) {
            int idx = c * 16 + sg * 4 + k2;
            o[k2] = rbuf[0][idx] + rbuf[1][idx] + rbuf[2][idx] + rbuf[3][idx];
        }
        *reinterpret_cast<f32x4*>(ref + (((size_t)a * 16 + b) * 64 + c) * 1024 + stile * 16 + sg * 4) = o;
    }
}

// ---------- kernel 4: fused bicubic upsample, 4-px vectorized ----------
__global__ void __launch_bounds__(256) k_up3(const float* __restrict__ ref, const float* __restrict__ wu,
                                             const float* __restrict__ x, const float* __restrict__ y,
                                             const float* __restrict__ g1, const float* __restrict__ g2,
                                             const float* __restrict__ g3, const float* __restrict__ g4,
                                             __hip_bfloat16* __restrict__ cat4) {
    int bid = blockIdx.x;               // b*128 + c*2 + pair
    int b = bid >> 7;
    int c = (bid >> 1) & 63;
    int pair = bid & 1;
    int aA = pair ? 1 : 0;
    int aB = pair ? 2 : 3;
    const float* orig = (pair ? y : x) + ((size_t)b * 64 + c) * HW;
    float gA = (pair ? g2 : g1)[0];
    float gB = (pair ? g3 : g4)[0];
    const float* srcA = ref + (((size_t)aA * 16 + b) * 64 + c) * 1024;
    const float* srcB = ref + (((size_t)aB * 16 + b) * 64 + c) * 1024;

    __shared__ float wsh[512];
    __shared__ float rch[2][1024];
    __shared__ float tmp[2][128][32];
    int tid = threadIdx.x;
    for (int i = tid; i < 512; i += 256) wsh[i] = wu[i];
    {
        float4 a4 = reinterpret_cast<const float4*>(srcA)[tid];
        float4 b4 = reinterpret_cast<const float4*>(srcB)[tid];
        reinterpret_cast<float4*>(&rch[0][0])[tid] = a4;
        reinterpret_cast<float4*>(&rch[1][0])[tid] = b4;
    }
    __syncthreads();

    #pragma unroll
    for (int it = 0; it < 4; ++it) {
        int task = tid + it * 256;
        int u = task >> 5, xx = task & 31;
        float w0[5], w1[5];
        #pragma unroll
        for (int m = 0; m < 5; ++m) {
            int j = u - 2 + m;
            bool ok = (j >= 0) && (j < 32);
            w0[m] = ok ? rch[0][j * 32 + xx] : 0.f;
            w1[m] = ok ? rch[1][j * 32 + xx] : 0.f;
        }
        #pragma unroll
        for (int r = 0; r < 4; ++r) {
            int oy = 4 * u + r;
            int mo = r >> 1;
            float a0 = 0.f, a1 = 0.f;
            #pragma unroll
            for (int k = 0; k < 4; ++k) {
                float wv = wsh[oy * 4 + k];
                a0 += wv * w0[mo + k];
                a1 += wv * w1[mo + k];
            }
            tmp[0][oy][xx] = a0;
            tmp[1][oy][xx] = a1;
        }
    }
    __syncthreads();

    size_t obA = ((size_t)b * 256 + aA * 64 + c) * HW;
    size_t obB = ((size_t)b * 256 + aB * 64 + c) * HW;
    unsigned short* cat = (unsigned short*)cat4;
    #pragma unroll
    for (int it = 0; it < 16; ++it) {
        int task = tid + it * 256;
        int oy = task >> 5, t = task & 31;
        float u0[5], u1[5];
        #pragma unroll
        for (int m = 0; m < 5; ++m) {
            int j = t - 2 + m;
            bool ok = (j >= 0) && (j < 32);
            u0[m] = ok ? tmp[0][oy][j] : 0.f;
            u1[m] = ok ? tmp[1][oy][j] : 0.f;
        }
        float4 ov = *reinterpret_cast<const float4*>(orig + oy * 128 + t * 4);
        float ovr[4] = {ov.x, ov.y, ov.z, ov.w};
        u16x4 oA, oB;
        #pragma unroll
        for (int r = 0; r < 4; ++r) {
            int ox = 4 * t + r;
            int mo = r >> 1;
            float a0 = 0.f, a1 = 0.f;
            #pragma unroll
            for (int k = 0; k < 4; ++k) {
                float wv = wsh[ox * 4 + k];
                a0 += wv * u0[mo + k];
                a1 += wv * u1[mo + k];
            }
            oA[r] = f2bf(gA * a0 + ovr[r]);
            oB[r] = f2bf(gB * a1 + ovr[r]);
        }
        *reinterpret_cast<u16x4*>(&cat[obA + oy * 128 + t * 4]) = oA;
        *reinterpret_cast<u16x4*>(&cat[obB + oy * 128 + t * 4]) = oB;
    }
}

// ---------- kernel 5: fused spatial attention (mean/max + 3x3 conv + sigmoid + scale) ----------
__global__ void __launch_bounds__(256) k_spa(const float* __restrict__ x, const float* __restrict__ y,
                                             const float* __restrict__ saw_r, const float* __restrict__ saw_i,
                                             unsigned short* __restrict__ sxy) {
    int bid = blockIdx.x;               // img*128 + b*8 + chunk
    int img = bid >> 7;
    int rem = bid & 127;
    int b = rem >> 3;
    int chunk = rem & 7;
    const float* src = (img ? y : x) + (size_t)b * 64 * HW;
    const float* w = img ? saw_i : saw_r;
    int part = img ? 0 : 1;
    int gy0 = chunk * 16;

    __shared__ float avgsh[18 * 128];
    __shared__ float maxsh[18 * 128];
    __shared__ float sigsh[16 * 128];
    __shared__ float wsh[18];
    int tid = threadIdx.x;
    if (tid < 18) wsh[tid] = w[tid];

    #pragma unroll
    for (int it = 0; it < 3; ++it) {
        int task = tid + it * 256;
        if (task < 576) {
            int r = task >> 5;
            int q4 = task & 31;
            int gy = gy0 - 1 + r;
            float sx = 0.f, sy = 0.f, sz = 0.f, sw = 0.f;
            float mxx = 0.f, mxy = 0.f, mxz = 0.f, mxw2 = 0.f;
            if (gy >= 0 && gy < 128) {
                mxx = mxy = mxz = mxw2 = -1e30f;
                const float* p = src + gy * 128 + q4 * 4;
                for (int c = 0; c < 64; ++c) {
                    float4 v = *reinterpret_cast<const float4*>(p + (size_t)c * HW);
                    sx += v.x; sy += v.y; sz += v.z; sw += v.w;
                    mxx = fmaxf(mxx, v.x); mxy = fmaxf(mxy, v.y);
                    mxz = fmaxf(mxz, v.z); mxw2 = fmaxf(mxw2, v.w);
                }
                sx *= (1.f / 64.f); sy *= (1.f / 64.f); sz *= (1.f / 64.f); sw *= (1.f / 64.f);
            }
            int o = r * 128 + q4 * 4;
            avgsh[o + 0] = sx; avgsh[o + 1] = sy; avgsh[o + 2] = sz; avgsh[o + 3] = sw;
            maxsh[o + 0] = mxx; maxsh[o + 1] = mxy; maxsh[o + 2] = mxz; maxsh[o + 3] = mxw2;
        }
    }
    __syncthreads();

    #pragma unroll
    for (int it = 0; it < 8; ++it) {
        int px = tid + it * 256;
        int ly = px >> 7, xx = px & 127;
        float acc = 0.f;
        #pragma unroll
        for (int dy = 0; dy < 3; ++dy) {
            int r = ly + dy;
            #pragma unroll
            for (int dx = 0; dx < 3; ++dx) {
                int ix = xx + dx - 1;
                if (ix >= 0 && ix < 128) {
                    acc += wsh[dy * 3 + dx] * avgsh[r * 128 + ix];
                    acc += wsh[9 + dy * 3 + dx] * maxsh[r * 128 + ix];
                }
            }
        }
        sigsh[px] = 1.f / (1.f + expf(-acc));
    }
    __syncthreads();

    float sg[8];
    #pragma unroll
    for (int k = 0; k < 8; ++k) sg[k] = 1.f + sigsh[tid * 8 + k];
    unsigned short* dst = sxy + ((size_t)b * 128 + part * 64) * HW + gy0 * 128;
    const float* sb = src + gy0 * 128;
    for (int c = 0; c < 64; ++c) {
        #pragma unroll
        for (int j = 0; j < 2; ++j) {
            int px = tid * 8 + j * 4;
            float4 v = *reinterpret_cast<const float4*>(sb + (size_t)c * HW + px);
            u16x4 o = {f2bf(v.x * sg[j * 4 + 0]), f2bf(v.y * sg[j * 4 + 1]),
                       f2bf(v.z * sg[j * 4 + 2]), f2bf(v.w * sg[j * 4 + 3])};
            *reinterpret_cast<u16x4*>(dst + (size_t)c * HW + px) = o;
        }
    }
}

// ---------- kernel 9: 3x3 conv via MFMA, LDS weights, 8-row tile (R17) ----------
// R17 change vs R12: tile height 4 -> 8 output rows, 16 waves (1024 thr), 1 block/CU.
// MFMA work per SIMD per cb doubles against the same stage latency -> stall fraction
// halves; halo 10 staged rows / 8 output (1.25x vs 1.5x); weight stage amortized 2x.
// LDS: xs[10*133*32]=85.1KB + ws2 36.9KB = 122KB. VGPR ~88 < 128 cap @ 4 waves/SIMD.
// (Register prefetch across the MFMA loop remains forbidden: R7/R8/R15 all failed.)
template<int CIBLKS, bool OBF16>
__global__ void __launch_bounds__(1024, 1) k_conv(const unsigned short* __restrict__ srcA, int cinA,
                                                  const unsigned short* __restrict__ srcB,
                                                  const unsigned short* __restrict__ wpk,
                                                  const float* __restrict__ bias,
                                                  void* __restrict__ outp) {
    const int cinB = CIBLKS * 32 - cinA;
    int bid = blockIdx.x;
    int b = bid >> 4, rt = bid & 15;
    int y0 = rt * 8;
    int tid = threadIdx.x;
    int lane = tid & 63, w = tid >> 6;       // w in 0..15
    int l15 = lane & 15, qg = (lane >> 4) & 3;
    int wr = w >> 1, wc = w & 1;             // wr in 0..7

    __shared__ __align__(16) unsigned short xs[10 * 133 * 32];
    __shared__ __align__(16) unsigned short ws2[9 * 4 * 64 * 8];

    // zero halo cols 0 and 129 (rows 0..9, all 4 slots)
    if (tid < 80) {
        int r = tid >> 3;
        int rem = tid & 7;
        int col = (rem >> 2) ? 129 : 0;
        int q = rem & 3;
        int slot = q ^ ((col >> 2) & 3);
        u16x8 z = (u16x8)0;
        *reinterpret_cast<u16x8*>(&xs[(r * 133 + col) * 32 + slot * 8]) = z;
    }

    f32x4 acc[4][4] = {};
    const bf16x8* wp = reinterpret_cast<const bf16x8*>(wpk);

    for (int cb = 0; cb < CIBLKS; ++cb) {
        __syncthreads();
        // ---- stage weights (2304 x 16B over 1024 threads) ----
        {
            const bf16x8* wsrc = wp + (size_t)cb * 2304;
            bf16x8* wdst = reinterpret_cast<bf16x8*>(ws2);
            wdst[tid] = wsrc[tid];
            wdst[tid + 1024] = wsrc[tid + 1024];
            if (tid < 256) wdst[tid + 2048] = wsrc[tid + 2048];
        }
        // ---- stage X: 10 rows x 128 px x 32 ci (1280 tasks, 8 ci x 4 px each) ----
        #pragma unroll
        for (int tt = 0; tt < 2; ++tt) {
            int task = tid + tt * 1024;
            if (task < 1280) {
                int q8 = task / 320;            // ci octet 0..3
                int rr = (task % 320) >> 5;     // row 0..9
                int xq = task & 31;             // px quad
                int yy = y0 - 1 + rr;
                int x0 = xq * 4;
                int ci0 = cb * 32 + q8 * 8;
                u16x4 v[8];
                if (yy >= 0 && yy < 128) {
                    const unsigned short* sp;
                    if (ci0 < cinA) sp = srcA + ((size_t)b * cinA + ci0) * HW;
                    else            sp = srcB + ((size_t)b * cinB + (ci0 - cinA)) * HW;
                    sp += yy * 128 + x0;
                    #pragma unroll
                    for (int p = 0; p < 8; ++p)
                        v[p] = *reinterpret_cast<const u16x4*>(sp + p * HW);
                } else {
                    #pragma unroll
                    for (int p = 0; p < 8; ++p) v[p] = (u16x4)0;
                }
                #pragma unroll
                for (int i = 0; i < 4; ++i) {
                    int d = (i + xq) & 3;
                    int col = x0 + 1 + d;
                    int slot = q8 ^ ((col >> 2) & 3);
                    u16x8 o;
                    #pragma unroll
                    for (int p = 0; p < 8; ++p) o[p] = v[p][d];
                    *reinterpret_cast<u16x8*>(&xs[(rr * 133 + col) * 32 + slot * 8]) = o;
                }
            }
        }
        __syncthreads();
        // ---- 9 K-steps of K=32 ----
        __builtin_amdgcn_s_setprio(1);
        #pragma unroll
        for (int ky = 0; ky < 3; ++ky) {
            #pragma unroll
            for (int kx = 0; kx < 3; ++kx) {
                int kk = ky * 3 + kx;
                bf16x8 afr[4];
                #pragma unroll
                for (int ct = 0; ct < 4; ++ct)
                    afr[ct] = *reinterpret_cast<const bf16x8*>(&ws2[((kk * 4 + ct) * 64 + lane) * 8]);
                int row = wr + ky;
                bf16x8 bfr[4];
                #pragma unroll
                for (int nt = 0; nt < 4; ++nt) {
                    int col = wc * 64 + nt * 16 + l15 + kx;
                    int slot = qg ^ ((col >> 2) & 3);
                    bfr[nt] = *reinterpret_cast<const bf16x8*>(&xs[(row * 133 + col) * 32 + slot * 8]);
                }
                #pragma unroll
                for (int ct = 0; ct < 4; ++ct)
                    #pragma unroll
                    for (int nt = 0; nt < 4; ++nt)
                        acc[ct][nt] = __builtin_amdgcn_mfma_f32_16x16x32_bf16(afr[ct], bfr[nt], acc[ct][nt], 0, 0, 0);
            }
        }
        __builtin_amdgcn_s_setprio(0);
    }

    int row_out = y0 + wr;
    #pragma unroll
    for (int ct = 0; ct < 4; ++ct) {
        float4 bi = *reinterpret_cast<const float4*>(bias + ct * 16 + qg * 4);
        #pragma unroll
        for (int nt = 0; nt < 4; ++nt) {
            int col_out = wc * 64 + nt * 16 + l15;
            #pragma unroll
            for (int reg = 0; reg < 4; ++reg) {
                int co = ct * 16 + qg * 4 + reg;
                float bv = (reg == 0) ? bi.x : (reg == 1) ? bi.y : (reg == 2) ? bi.z : bi.w;
                float v = fmaxf(acc[ct][nt][reg] + bv, 0.f);
                size_t off = ((size_t)b * 64 + co) * HW + row_out * 128 + col_out;
                if (OBF16) ((unsigned short*)outp)[off] = f2bf(v);
                else       ((float*)outp)[off] = v;
            }
        }
    }
}

// ---------- launch ----------
extern "C" void kernel_launch(void* const* d_in, const int* in_sizes, int n_in,
                              void* d_out, int out_size, void* d_ws, size_t ws_size,
                              hipStream_t stream) {
    const float* x = (const float*)d_in[0];
    const float* y = (const float*)d_in[1];

    const float* qw[6]; const float* qs[6];
    QkvBias qb;
    for (int q = 0; q < 6; q++) {
        qw[q] = (const float*)d_in[2 + 3 * q];
        qs[q] = (const float*)d_in[3 + 3 * q];
        qb.b[q] = (const float*)d_in[4 + 3 * q];
    }
    const float* red_w = (const float*)d_in[20];
    const float* red_s = (const float*)d_in[21];
    const float* red_b = (const float*)d_in[22];
    const float* sec_w = (const float*)d_in[23];
    const float* sec_s = (const float*)d_in[24];
    const float* sec_b = (const float*)d_in[25];
    const float* g1 = (const float*)d_in[26];
    const float* g2 = (const float*)d_in[27];
    const float* g3 = (const float*)d_in[28];
    const float* g4 = (const float*)d_in[29];
    const float* sa_r_w = (const float*)d_in[30];
    const float* sa_i_w = (const float*)d_in[31];

    // ---- workspace layout ----
    float* WD = (float*)d_ws;                       // 512
    float* WU = WD + 512;                           // 512
    float* SIG = WU + 512;                          // 524288 (unused after fusion)
    float* MM = SIG + 524288;                       // 1048576 (unused after fusion)
    float* REF = MM + 1048576;                      // 4194304
    unsigned short* WPKR = (unsigned short*)(REF + 4194304);  // 147456
    unsigned short* WPKS = WPKR + 147456;           // 110592
    unsigned short* WPKQ = WPKS + 110592;           // 221184
    unsigned short* REB = WPKQ + 221184;            // 2097152
    unsigned short* QT  = REB + 2097152;            // 2097152  [2][16][1024][64]
    unsigned short* KT  = QT + 2097152;             // 2097152  [2][16][1024][64]
    unsigned short* VN  = KT + 2097152;             // 2097152  [2][16][64][1024]
    unsigned short* GATT = VN + 2097152;            // 16777216
    unsigned short* CAT4 = GATT + 16777216;         // 67108864
    // fragment buffers alias the CAT4 region (dead until k_up3)
    unsigned short* QTF = CAT4;                     // 2097152
    unsigned short* KTF = CAT4 + 2097152;           // 2097152
    unsigned short* VF  = CAT4 + 4194304;           // 3145728
    unsigned short* SECXY = CAT4;                   // alias (after red conv)

    k_init<<<1, 256, 0, stream>>>(WD, WU);
    k_down<<<2 * 16 * 64, 256, 0, stream>>>(x, y, WD, REB);
    for (int q = 0; q < 6; q++)
        k_wpack<<<18, 256, 0, stream>>>(qw[q], qs[q], WPKQ + (size_t)q * 36864, 64);
    k_wpackc<<<72, 256, 0, stream>>>(red_w, red_s, WPKR, 256);
    k_wpackc<<<54, 256, 0, stream>>>(sec_w, sec_s, WPKS, 192);
    k_qkv2<<<6 * 64, 256, 0, stream>>>(REB, WPKQ, qb, QT, KT, VN);
    k_packa<<<512, 256, 0, stream>>>(QT, KT, QTF, KTF);
    k_packv<<<128, 256, 0, stream>>>(VN, VF);
    k_attn3<<<4 * 16 * 64, 256, 0, stream>>>(QTF, KTF, VF, REF);
    k_up3<<<16 * 128, 256, 0, stream>>>(REF, WU, x, y, g1, g2, g3, g4, (__hip_bfloat16*)CAT4);
    k_conv<8, true><<<16 * 16, 1024, 0, stream>>>(CAT4, 256, CAT4, WPKR, red_b, GATT);
    k_spa<<<2 * 16 * 8, 256, 0, stream>>>(x, y, sa_r_w, sa_i_w, SECXY);
    k_conv<6, false><<<16 * 16, 1024, 0, stream>>>(GATT, 64, SECXY, WPKS, sec_b, d_out);
}

// Round 19
// 515.543 us; speedup vs baseline: 1.1358x; 1.1358x over previous
//
#include <hip/hip_runtime.h>
#include <hip/hip_bf16.h>

// ---------- constants ----------
#define B 16
#define C 64
#define H 128
#define W 128
#define S 32
#define S2 1024
#define HW 16384

typedef __attribute__((ext_vector_type(8))) short bf16x8;
typedef __attribute__((ext_vector_type(4))) float f32x4;
typedef __attribute__((ext_vector_type(8))) unsigned short u16x8;
typedef __attribute__((ext_vector_type(4))) unsigned short u16x4;

static __device__ __forceinline__ unsigned short f2bf(float v) {
    __hip_bfloat16 h = __float2bfloat16(v);
    return *reinterpret_cast<unsigned short*>(&h);
}
static __device__ __forceinline__ float bf2f(unsigned short u) {
    union { unsigned int i; float f; } cv;
    cv.i = ((unsigned int)u) << 16;
    return cv.f;
}

// ---------- Keys cubic kernel (a = -0.5) ----------
__device__ __forceinline__ float keys(float t) {
    t = fabsf(t);
    if (t >= 2.f) return 0.f;
    float t2 = t * t, t3 = t2 * t;
    if (t >= 1.f) return -0.5f * t3 + 2.5f * t2 - 4.f * t + 2.f;
    return 1.5f * t3 - 2.5f * t2 + 1.f;
}

// ---------- kernel 0: precompute resize weights ----------
__global__ void k_init(float* __restrict__ wd, float* __restrict__ wu) {
    int tid = threadIdx.x;
    if (tid < 32) {
        int i = tid;
        float sf = 4.f * i + 1.5f;
        int j0 = 4 * i - 6;
        float w[16];
        float s = 0.f;
        for (int k = 0; k < 16; k++) {
            int j = j0 + k;
            float v = 0.f;
            if (j >= 0 && j < 128) v = keys((sf - (float)j) * 0.25f);
            w[k] = v; s += v;
        }
        float inv = 1.f / s;
        for (int k = 0; k < 16; k++) wd[i * 16 + k] = w[k] * inv;
    } else if (tid >= 64 && tid < 192) {
        int i = tid - 64;
        float sf = 0.25f * i - 0.375f;
        int j0 = (int)floorf(sf) - 1;
        float w[4];
        float s = 0.f;
        for (int k = 0; k < 4; k++) {
            int j = j0 + k;
            float v = 0.f;
            if (j >= 0 && j < 32) v = keys(sf - (float)j);
            w[k] = v; s += v;
        }
        float inv = 1.f / s;
        for (int k = 0; k < 4; k++) wu[i * 4 + k] = w[k] * inv;
    }
}

// ---------- kernel 1: bicubic downsample (LDS-staged, conflict-free) ----------
__global__ void __launch_bounds__(256) k_down(const float* __restrict__ x, const float* __restrict__ y,
                                              const float* __restrict__ wd, unsigned short* __restrict__ re) {
    int bid = blockIdx.x;
    int img = bid >> 10;
    int bc = bid & 1023;
    const float* src = (img ? y : x) + (size_t)bc * HW;
    __shared__ unsigned short xsrc[128 * 128];
    __shared__ float tmp[32 * 160];
    __shared__ float wsh[512];
    int tid = threadIdx.x;
    for (int i = tid; i < 512; i += 256) wsh[i] = wd[i];
    #pragma unroll
    for (int it = 0; it < 16; ++it) {
        int i4 = (tid + it * 256) * 4;
        float4 v = *reinterpret_cast<const float4*>(src + i4);
        u16x4 o = {f2bf(v.x), f2bf(v.y), f2bf(v.z), f2bf(v.w)};
        *reinterpret_cast<u16x4*>(&xsrc[i4]) = o;
    }
    __syncthreads();
    #pragma unroll
    for (int it = 0; it < 16; ++it) {
        int idx = tid + it * 256;
        int oy = idx >> 7, xx = idx & 127;
        int j0 = 4 * oy - 6;
        float acc = 0.f;
        #pragma unroll
        for (int k = 0; k < 16; k++) {
            int j = j0 + k;
            if (j >= 0 && j < 128) acc += wsh[oy * 16 + k] * bf2f(xsrc[j * 128 + xx]);
        }
        tmp[oy * 160 + (xx & 3) * 40 + (xx >> 2)] = acc;
    }
    __syncthreads();
    #pragma unroll
    for (int it = 0; it < 4; ++it) {
        int idx = tid + it * 256;
        int oy = idx >> 5, ox = idx & 31;
        int j0 = 4 * ox - 6;
        float acc = 0.f;
        #pragma unroll
        for (int k = 0; k < 16; k++) {
            int j = j0 + k;
            if (j >= 0 && j < 128) acc += wsh[ox * 16 + k] * tmp[oy * 160 + (j & 3) * 40 + (j >> 2)];
        }
        re[(size_t)bid * 1024 + idx] = f2bf(acc);
    }
}

// ---------- weight pack (interleaved k-map) for qkv convs ----------
__global__ void k_wpack(const float* __restrict__ w, const float* __restrict__ s,
                        unsigned short* __restrict__ wpk, int cin) {
    int ks = blockIdx.x;
    int tid = threadIdx.x;
    int lane = tid & 63, ct = tid >> 6;
    int cb = ks / 9, kk = ks % 9;
    int m = ct * 16 + (lane & 15);
    int qq = lane >> 4;
    float sc = s[m];
    u16x8 outv;
    #pragma unroll
    for (int j = 0; j < 8; ++j) {
        int k = qq * 4 + (j & 3) + ((j >> 2) << 4);
        int ci = cb * 32 + k;
        float v = w[((size_t)m * cin + ci) * 9 + kk] * sc;
        outv[j] = f2bf(v);
    }
    *reinterpret_cast<u16x8*>(wpk + ((size_t)(ks * 4 + ct) * 64 + lane) * 8) = outv;
}

// ---------- weight pack (contiguous-8 k-map) for red/sec convs ----------
__global__ void k_wpackc(const float* __restrict__ w, const float* __restrict__ s,
                         unsigned short* __restrict__ wpk, int cin) {
    int ks = blockIdx.x;
    int tid = threadIdx.x;
    int lane = tid & 63, ct = tid >> 6;
    int cb = ks / 9, kk = ks % 9;
    int m = ct * 16 + (lane & 15);
    int qq = (lane >> 4) & 3;
    float sc = s[m];
    u16x8 outv;
    #pragma unroll
    for (int j = 0; j < 8; ++j) {
        int ci = cb * 32 + qq * 8 + j;
        float v = w[((size_t)m * cin + ci) * 9 + kk] * sc;
        outv[j] = f2bf(v);
    }
    *reinterpret_cast<u16x8*>(wpk + ((size_t)(ks * 4 + ct) * 64 + lane) * 8) = outv;
}

// ---------- kernel 2: six QKV 3x3 convs via MFMA, outputs routed per q ----------
struct QkvBias { const float* b[6]; };

__global__ void __launch_bounds__(256) k_qkv2(const unsigned short* __restrict__ re,
                                              const unsigned short* __restrict__ wpkq,
                                              QkvBias bias,
                                              unsigned short* __restrict__ qt,
                                              unsigned short* __restrict__ kt,
                                              unsigned short* __restrict__ vn) {
    int bid = blockIdx.x;                 // q*64 + b*4 + quad
    int q = bid >> 6;
    int rem = bid & 63;
    int b = rem >> 2;
    int quad = rem & 3;
    int img = (q < 3) ? 0 : 1;
    const unsigned short* src = re + ((size_t)(img * 16 + b)) * 64 * 1024;
    const bf16x8* wp = reinterpret_cast<const bf16x8*>(wpkq + (size_t)q * 18 * 4 * 64 * 8);
    const float* bptr = bias.b[q];

    int tid = threadIdx.x;
    int lane = tid & 63, w = tid >> 6;
    int l15 = lane & 15, qg = lane >> 4;

    __shared__ __align__(16) unsigned short xs[10 * 34 * 32];

    if (tid < 160) {
        int r = tid >> 4;
        int inner = tid & 15;
        int col = (inner >> 3) ? 33 : 0;
        int qd = inner & 7;
        int sbase = ((qd & 3) << 3) + ((qd >> 2) << 2);
        int sbs = sbase ^ ((((col >> 1) & 3)) << 3);
        u16x4 z = {0, 0, 0, 0};
        *reinterpret_cast<u16x4*>(&xs[(r * 34 + col) * 32 + sbs]) = z;
    }

    f32x4 acc[4][4] = {};

    for (int cb = 0; cb < 2; ++cb) {
        __syncthreads();
        #pragma unroll
        for (int tt = 0; tt < 2; ++tt) {
            int task = tid + tt * 256;
            if (task < 320) {
                int r = task >> 5;
                int inner = task & 31;
                int qd = inner >> 2, xc = inner & 3;
                int yy = quad * 8 - 1 + r;
                int x0 = xc * 8;
                int ci0 = cb * 32 + qd * 4;
                u16x8 v0, v1, v2, v3;
                if (yy >= 0 && yy < 32) {
                    const unsigned short* sp = src + (size_t)ci0 * 1024 + yy * 32 + x0;
                    v0 = *reinterpret_cast<const u16x8*>(sp);
                    v1 = *reinterpret_cast<const u16x8*>(sp + 1024);
                    v2 = *reinterpret_cast<const u16x8*>(sp + 2048);
                    v3 = *reinterpret_cast<const u16x8*>(sp + 3072);
                } else {
                    v0 = (u16x8)0; v1 = (u16x8)0; v2 = (u16x8)0; v3 = (u16x8)0;
                }
                int sbase = ((qd & 3) << 3) + ((qd >> 2) << 2);
                #pragma unroll
                for (int dx = 0; dx < 8; ++dx) {
                    int col = x0 + 1 + dx;
                    int sbs = sbase ^ (((col >> 1) & 3) << 3);
                    u16x4 pk = {v0[dx], v1[dx], v2[dx], v3[dx]};
                    *reinterpret_cast<u16x4*>(&xs[(r * 34 + col) * 32 + sbs]) = pk;
                }
            }
        }
        __syncthreads();
        #pragma unroll
        for (int ky = 0; ky < 3; ++ky) {
            #pragma unroll
            for (int kx = 0; kx < 3; ++kx) {
                int ksidx = cb * 9 + ky * 3 + kx;
                bf16x8 afr[4];
                #pragma unroll
                for (int ct = 0; ct < 4; ++ct)
                    afr[ct] = wp[((size_t)(ksidx * 4 + ct) << 6) + lane];
                bf16x8 bfr[4];
                #pragma unroll
                for (int nt = 0; nt < 4; ++nt) {
                    int rp = nt >> 1;
                    int col = (nt & 1) * 16 + l15 + kx;
                    int r = w * 2 + rp + ky;
                    int sbs = (qg ^ ((col >> 1) & 3)) << 3;
                    bfr[nt] = *reinterpret_cast<const bf16x8*>(&xs[(r * 34 + col) * 32 + sbs]);
                }
                #pragma unroll
                for (int ct = 0; ct < 4; ++ct)
                    #pragma unroll
                    for (int nt = 0; nt < 4; ++nt)
                        acc[ct][nt] = __builtin_amdgcn_mfma_f32_16x16x32_bf16(afr[ct], bfr[nt], acc[ct][nt], 0, 0, 0);
            }
        }
    }

    // epilogue
    int pair = (q < 3) ? 0 : 1;
    bool isV = (q == 2 || q == 5);
    unsigned short* dst;
    if (q == 0 || q == 3)      dst = qt + ((size_t)(pair * 16 + b)) * 65536;
    else if (q == 1 || q == 4) dst = kt + ((size_t)(pair * 16 + b)) * 65536;
    else                       dst = vn + ((size_t)(pair * 16 + b)) * 65536;
    #pragma unroll
    for (int ct = 0; ct < 4; ++ct) {
        float4 bi = *reinterpret_cast<const float4*>(bptr + ct * 16 + qg * 4);
        #pragma unroll
        for (int nt = 0; nt < 4; ++nt) {
            int pxl = nt * 16 + l15;
            int rowg = quad * 8 + w * 2 + (pxl >> 5);
            int colg = pxl & 31;
            int px = rowg * 32 + colg;
            #pragma unroll
            for (int reg = 0; reg < 4; ++reg) {
                int co = ct * 16 + qg * 4 + reg;
                float bv = (reg == 0) ? bi.x : (reg == 1) ? bi.y : (reg == 2) ? bi.z : bi.w;
                float v = fmaxf(acc[ct][nt][reg] + bv, 0.f);
                unsigned short bf = f2bf(v);
                if (isV) dst[(size_t)co * 1024 + px] = bf;
                else     dst[(size_t)px * 64 + co] = bf;
            }
        }
    }
}

// ---------- pack Q/K (px-major [1024][64]) into MFMA fragment order ----------
__global__ void k_packa(const unsigned short* __restrict__ qt,
                        const unsigned short* __restrict__ kt,
                        unsigned short* __restrict__ qtf,
                        unsigned short* __restrict__ ktf) {
    int bid = blockIdx.x;            // tsel*128 + b*8 + seg
    int tsel = bid >> 7;
    int b = (bid >> 3) & 15;
    int seg = bid & 7;
    int tid = threadIdx.x;
    int lane = tid & 63, w = tid >> 6;
    int l15 = lane & 15, qg = lane >> 4;
    const unsigned short* src = (tsel < 2 ? qt : kt) + ((size_t)((tsel & 1) * 16 + b)) * 65536;
    unsigned short* dst = (tsel < 2 ? qtf : ktf) + ((size_t)((tsel & 1) * 16 + b)) * 65536;
    #pragma unroll
    for (int it = 0; it < 4; ++it) {
        int fi = seg * 16 + it * 4 + w;
        int tf = fi >> 1, kb = fi & 1;
        const unsigned short* row = src + (size_t)(tf * 16 + l15) * 64 + kb * 32 + qg * 4;
        u16x4 a0 = *reinterpret_cast<const u16x4*>(row);
        u16x4 a1 = *reinterpret_cast<const u16x4*>(row + 16);
        u16x8 o;
        #pragma unroll
        for (int j = 0; j < 4; ++j) { o[j] = a0[j]; o[4 + j] = a1[j]; }
        *reinterpret_cast<u16x8*>(dst + (size_t)fi * 512 + lane * 8) = o;
    }
}

// ---------- pack V (co-major [64][1024]) into fragment order; also builds DV=RV+IV ----------
__global__ void k_packv(const unsigned short* __restrict__ vn,
                        unsigned short* __restrict__ vf) {
    int bid = blockIdx.x;            // b*8 + seg
    int b = bid >> 3;
    int seg = bid & 7;
    int tid = threadIdx.x;
    int lane = tid & 63, w = tid >> 6;
    int l15 = lane & 15, qg = lane >> 4;
    const unsigned short* rv = vn + (size_t)b * 65536;
    const unsigned short* iv = vn + (size_t)(16 + b) * 65536;
    #pragma unroll
    for (int it = 0; it < 4; ++it) {
        int fi = seg * 16 + it * 4 + w;
        int cf = fi >> 5, tq = fi & 31;
        int c = cf * 16 + l15;
        size_t roff = (size_t)c * 1024 + tq * 32 + qg * 4;
        u16x4 r0 = *reinterpret_cast<const u16x4*>(rv + roff);
        u16x4 r1 = *reinterpret_cast<const u16x4*>(rv + roff + 16);
        u16x4 i0 = *reinterpret_cast<const u16x4*>(iv + roff);
        u16x4 i1 = *reinterpret_cast<const u16x4*>(iv + roff + 16);
        u16x8 orv, oiv, odv;
        #pragma unroll
        for (int j = 0; j < 4; ++j) {
            orv[j] = r0[j]; orv[4 + j] = r1[j];
            oiv[j] = i0[j]; oiv[4 + j] = i1[j];
            odv[j] = f2bf(bf2f(r0[j]) + bf2f(i0[j]));
            odv[4 + j] = f2bf(bf2f(r1[j]) + bf2f(i1[j]));
        }
        size_t eoff = ((size_t)b * 128 + fi) * 512 + lane * 8;
        *reinterpret_cast<u16x8*>(vf + eoff) = orv;
        *reinterpret_cast<u16x8*>(vf + 1048576 + eoff) = oiv;
        *reinterpret_cast<u16x8*>(vf + 2097152 + eoff) = odv;
    }
}

// ---------- kernel 3: MFMA attention, all operands in fragment layout ----------
__global__ void __launch_bounds__(256) k_attn3(const unsigned short* __restrict__ QTF,
                                               const unsigned short* __restrict__ KTF,
                                               const unsigned short* __restrict__ VF,
                                               float* __restrict__ ref) {
    int bid = blockIdx.x;                  // a*1024 + b*64 + stile
    int a = bid >> 10;
    int b = (bid >> 6) & 15;
    int stile = bid & 63;
    int qsel = (a == 0 || a == 2) ? 0 : 1;
    int ksel = (a == 0 || a == 3) ? 0 : 1;
    int vsel = (a < 2) ? 2 : (a == 2 ? 0 : 1);

    int tid = threadIdx.x;
    int lane = tid & 63, w = tid >> 6;
    int l15 = lane & 15, qg = lane >> 4;

    const bf16x8* qf = reinterpret_cast<const bf16x8*>(QTF) + ((size_t)(qsel * 16 + b) * 128) * 64;
    const bf16x8* kf = reinterpret_cast<const bf16x8*>(KTF) + ((size_t)(ksel * 16 + b) * 128) * 64;
    const bf16x8* vfb = reinterpret_cast<const bf16x8*>(VF) + ((size_t)(vsel * 16 + b) * 128) * 64;

    __shared__ float mxw[4][16];
    __shared__ float smw[4][16];
    __shared__ float rbuf[4][64 * 16];

    bf16x8 bk0 = kf[(size_t)(stile * 2 + 0) * 64 + lane];
    bf16x8 bk1 = kf[(size_t)(stile * 2 + 1) * 64 + lane];
    f32x4 acc[16] = {};
    #pragma unroll
    for (int mf = 0; mf < 16; ++mf) {
        int tf = w * 16 + mf;
        bf16x8 a0 = qf[(size_t)(tf * 2 + 0) * 64 + lane];
        bf16x8 a1 = qf[(size_t)(tf * 2 + 1) * 64 + lane];
        acc[mf] = __builtin_amdgcn_mfma_f32_16x16x32_bf16(a0, bk0, acc[mf], 0, 0, 0);
        acc[mf] = __builtin_amdgcn_mfma_f32_16x16x32_bf16(a1, bk1, acc[mf], 0, 0, 0);
    }

    float mx = -1e30f;
    #pragma unroll
    for (int mf = 0; mf < 16; ++mf)
        #pragma unroll
        for (int r = 0; r < 4; ++r) mx = fmaxf(mx, acc[mf][r]);
    mx = fmaxf(mx, __shfl_xor(mx, 16));
    mx = fmaxf(mx, __shfl_xor(mx, 32));
    if (qg == 0) mxw[w][l15] = mx;
    __syncthreads();
    float M = fmaxf(fmaxf(mxw[0][l15], mxw[1][l15]), fmaxf(mxw[2][l15], mxw[3][l15]));
    float sm = 0.f;
    #pragma unroll
    for (int mf = 0; mf < 16; ++mf)
        #pragma unroll
        for (int r = 0; r < 4; ++r) {
            float e = __builtin_amdgcn_exp2f((acc[mf][r] - M) * 1.4426950408889634f);
            acc[mf][r] = e;
            sm += e;
        }
    sm += __shfl_xor(sm, 16);
    sm += __shfl_xor(sm, 32);
    if (qg == 0) smw[w][l15] = sm;
    __syncthreads();
    float inv = 1.f / (smw[0][l15] + smw[1][l15] + smw[2][l15] + smw[3][l15]);

    f32x4 pacc[4] = {};
    #pragma unroll
    for (int kk = 0; kk < 8; ++kk) {
        bf16x8 bp;
        #pragma unroll
        for (int j = 0; j < 4; ++j) {
            bp[j] = (short)f2bf(acc[2 * kk][j]);
            bp[4 + j] = (short)f2bf(acc[2 * kk + 1][j]);
        }
        #pragma unroll
        for (int cf = 0; cf < 4; ++cf) {
            bf16x8 av = vfb[(size_t)(cf * 32 + w * 8 + kk) * 64 + lane];
            pacc[cf] = __builtin_amdgcn_mfma_f32_16x16x32_bf16(av, bp, pacc[cf], 0, 0, 0);
        }
    }
    #pragma unroll
    for (int cf = 0; cf < 4; ++cf)
        #pragma unroll
        for (int r = 0; r < 4; ++r)
            rbuf[w][(cf * 16 + qg * 4 + r) * 16 + l15] = pacc[cf][r] * inv;
    __syncthreads();

    {
        int c = tid >> 2, sg = tid & 3;
        f32x4 o;
        #pragma unroll
        for (int k2 = 0; k2 < 4; ++k2) {
            int idx = c * 16 + sg * 4 + k2;
            o[k2] = rbuf[0][idx] + rbuf[1][idx] + rbuf[2][idx] + rbuf[3][idx];
        }
        *reinterpret_cast<f32x4*>(ref + (((size_t)a * 16 + b) * 64 + c) * 1024 + stile * 16 + sg * 4) = o;
    }
}

// ---------- kernel 4: fused bicubic upsample, 4-px vectorized ----------
__global__ void __launch_bounds__(256) k_up3(const float* __restrict__ ref, const float* __restrict__ wu,
                                             const float* __restrict__ x, const float* __restrict__ y,
                                             const float* __restrict__ g1, const float* __restrict__ g2,
                                             const float* __restrict__ g3, const float* __restrict__ g4,
                                             __hip_bfloat16* __restrict__ cat4) {
    int bid = blockIdx.x;               // b*128 + c*2 + pair
    int b = bid >> 7;
    int c = (bid >> 1) & 63;
    int pair = bid & 1;
    int aA = pair ? 1 : 0;
    int aB = pair ? 2 : 3;
    const float* orig = (pair ? y : x) + ((size_t)b * 64 + c) * HW;
    float gA = (pair ? g2 : g1)[0];
    float gB = (pair ? g3 : g4)[0];
    const float* srcA = ref + (((size_t)aA * 16 + b) * 64 + c) * 1024;
    const float* srcB = ref + (((size_t)aB * 16 + b) * 64 + c) * 1024;

    __shared__ float wsh[512];
    __shared__ float rch[2][1024];
    __shared__ float tmp[2][128][32];
    int tid = threadIdx.x;
    for (int i = tid; i < 512; i += 256) wsh[i] = wu[i];
    {
        float4 a4 = reinterpret_cast<const float4*>(srcA)[tid];
        float4 b4 = reinterpret_cast<const float4*>(srcB)[tid];
        reinterpret_cast<float4*>(&rch[0][0])[tid] = a4;
        reinterpret_cast<float4*>(&rch[1][0])[tid] = b4;
    }
    __syncthreads();

    #pragma unroll
    for (int it = 0; it < 4; ++it) {
        int task = tid + it * 256;
        int u = task >> 5, xx = task & 31;
        float w0[5], w1[5];
        #pragma unroll
        for (int m = 0; m < 5; ++m) {
            int j = u - 2 + m;
            bool ok = (j >= 0) && (j < 32);
            w0[m] = ok ? rch[0][j * 32 + xx] : 0.f;
            w1[m] = ok ? rch[1][j * 32 + xx] : 0.f;
        }
        #pragma unroll
        for (int r = 0; r < 4; ++r) {
            int oy = 4 * u + r;
            int mo = r >> 1;
            float a0 = 0.f, a1 = 0.f;
            #pragma unroll
            for (int k = 0; k < 4; ++k) {
                float wv = wsh[oy * 4 + k];
                a0 += wv * w0[mo + k];
                a1 += wv * w1[mo + k];
            }
            tmp[0][oy][xx] = a0;
            tmp[1][oy][xx] = a1;
        }
    }
    __syncthreads();

    size_t obA = ((size_t)b * 256 + aA * 64 + c) * HW;
    size_t obB = ((size_t)b * 256 + aB * 64 + c) * HW;
    unsigned short* cat = (unsigned short*)cat4;
    #pragma unroll
    for (int it = 0; it < 16; ++it) {
        int task = tid + it * 256;
        int oy = task >> 5, t = task & 31;
        float u0[5], u1[5];
        #pragma unroll
        for (int m = 0; m < 5; ++m) {
            int j = t - 2 + m;
            bool ok = (j >= 0) && (j < 32);
            u0[m] = ok ? tmp[0][oy][j] : 0.f;
            u1[m] = ok ? tmp[1][oy][j] : 0.f;
        }
        float4 ov = *reinterpret_cast<const float4*>(orig + oy * 128 + t * 4);
        float ovr[4] = {ov.x, ov.y, ov.z, ov.w};
        u16x4 oA, oB;
        #pragma unroll
        for (int r = 0; r < 4; ++r) {
            int ox = 4 * t + r;
            int mo = r >> 1;
            float a0 = 0.f, a1 = 0.f;
            #pragma unroll
            for (int k = 0; k < 4; ++k) {
                float wv = wsh[ox * 4 + k];
                a0 += wv * u0[mo + k];
                a1 += wv * u1[mo + k];
            }
            oA[r] = f2bf(gA * a0 + ovr[r]);
            oB[r] = f2bf(gB * a1 + ovr[r]);
        }
        *reinterpret_cast<u16x4*>(&cat[obA + oy * 128 + t * 4]) = oA;
        *reinterpret_cast<u16x4*>(&cat[obB + oy * 128 + t * 4]) = oB;
    }
}

// ---------- kernel 5: fused spatial attention (mean/max + 3x3 conv + sigmoid + scale) ----------
__global__ void __launch_bounds__(256) k_spa(const float* __restrict__ x, const float* __restrict__ y,
                                             const float* __restrict__ saw_r, const float* __restrict__ saw_i,
                                             unsigned short* __restrict__ sxy) {
    int bid = blockIdx.x;               // img*128 + b*8 + chunk
    int img = bid >> 7;
    int rem = bid & 127;
    int b = rem >> 3;
    int chunk = rem & 7;
    const float* src = (img ? y : x) + (size_t)b * 64 * HW;
    const float* w = img ? saw_i : saw_r;
    int part = img ? 0 : 1;
    int gy0 = chunk * 16;

    __shared__ float avgsh[18 * 128];
    __shared__ float maxsh[18 * 128];
    __shared__ float sigsh[16 * 128];
    __shared__ float wsh[18];
    int tid = threadIdx.x;
    if (tid < 18) wsh[tid] = w[tid];

    #pragma unroll
    for (int it = 0; it < 3; ++it) {
        int task = tid + it * 256;
        if (task < 576) {
            int r = task >> 5;
            int q4 = task & 31;
            int gy = gy0 - 1 + r;
            float sx = 0.f, sy = 0.f, sz = 0.f, sw = 0.f;
            float mxx = 0.f, mxy = 0.f, mxz = 0.f, mxw2 = 0.f;
            if (gy >= 0 && gy < 128) {
                mxx = mxy = mxz = mxw2 = -1e30f;
                const float* p = src + gy * 128 + q4 * 4;
                for (int c = 0; c < 64; ++c) {
                    float4 v = *reinterpret_cast<const float4*>(p + (size_t)c * HW);
                    sx += v.x; sy += v.y; sz += v.z; sw += v.w;
                    mxx = fmaxf(mxx, v.x); mxy = fmaxf(mxy, v.y);
                    mxz = fmaxf(mxz, v.z); mxw2 = fmaxf(mxw2, v.w);
                }
                sx *= (1.f / 64.f); sy *= (1.f / 64.f); sz *= (1.f / 64.f); sw *= (1.f / 64.f);
            }
            int o = r * 128 + q4 * 4;
            avgsh[o + 0] = sx; avgsh[o + 1] = sy; avgsh[o + 2] = sz; avgsh[o + 3] = sw;
            maxsh[o + 0] = mxx; maxsh[o + 1] = mxy; maxsh[o + 2] = mxz; maxsh[o + 3] = mxw2;
        }
    }
    __syncthreads();

    #pragma unroll
    for (int it = 0; it < 8; ++it) {
        int px = tid + it * 256;
        int ly = px >> 7, xx = px & 127;
        float acc = 0.f;
        #pragma unroll
        for (int dy = 0; dy < 3; ++dy) {
            int r = ly + dy;
            #pragma unroll
            for (int dx = 0; dx < 3; ++dx) {
                int ix = xx + dx - 1;
                if (ix >= 0 && ix < 128) {
                    acc += wsh[dy * 3 + dx] * avgsh[r * 128 + ix];
                    acc += wsh[9 + dy * 3 + dx] * maxsh[r * 128 + ix];
                }
            }
        }
        sigsh[px] = 1.f / (1.f + expf(-acc));
    }
    __syncthreads();

    float sg[8];
    #pragma unroll
    for (int k = 0; k < 8; ++k) sg[k] = 1.f + sigsh[tid * 8 + k];
    unsigned short* dst = sxy + ((size_t)b * 128 + part * 64) * HW + gy0 * 128;
    const float* sb = src + gy0 * 128;
    for (int c = 0; c < 64; ++c) {
        #pragma unroll
        for (int j = 0; j < 2; ++j) {
            int px = tid * 8 + j * 4;
            float4 v = *reinterpret_cast<const float4*>(sb + (size_t)c * HW + px);
            u16x4 o = {f2bf(v.x * sg[j * 4 + 0]), f2bf(v.y * sg[j * 4 + 1]),
                       f2bf(v.z * sg[j * 4 + 2]), f2bf(v.w * sg[j * 4 + 3])};
            *reinterpret_cast<u16x4*>(dst + (size_t)c * HW + px) = o;
        }
    }
}

// ---------- kernel 9: 3x3 conv via MFMA implicit GEMM, LDS-staged weights ----------
// R12 configuration — best measured: ~115us red / MfmaUtil 27% / VGPR 88 / no spill.
// Dead ends (documented, do not retry): register prefetch across the MFMA loop
// (R7 cap-thrash, R8 scratch spill, R15 VALU churn); split weight staging / extra
// barriers (R14); alternate slot hash (R13/R14); 1024-thread blocks (R18: VGPR
// capped at 64 -> accumulator spill); (512,4) (R5: 64-VGPR cap spill).
template<int CIBLKS, bool OBF16>
__global__ void __launch_bounds__(512, 1) k_conv(const unsigned short* __restrict__ srcA, int cinA,
                                                 const unsigned short* __restrict__ srcB,
                                                 const unsigned short* __restrict__ wpk,
                                                 const float* __restrict__ bias,
                                                 void* __restrict__ outp) {
    const int cinB = CIBLKS * 32 - cinA;
    int bid = blockIdx.x;
    int b = bid >> 5, rt = bid & 31;
    int y0 = rt * 4;
    int tid = threadIdx.x;
    int lane = tid & 63, w = tid >> 6;
    int l15 = lane & 15, qg = (lane >> 4) & 3;
    int wr = w >> 1, wc = w & 1;

    __shared__ __align__(16) unsigned short xs[6 * 133 * 32];
    __shared__ __align__(16) unsigned short ws2[9 * 4 * 64 * 8];

    if (tid < 48) {
        int r = tid >> 3;
        int rem = tid & 7;
        int col = (rem >> 2) ? 129 : 0;
        int q = rem & 3;
        int slot = q ^ ((col >> 2) & 3);
        u16x8 z = (u16x8)0;
        *reinterpret_cast<u16x8*>(&xs[(r * 133 + col) * 32 + slot * 8]) = z;
    }

    f32x4 acc[4][4] = {};
    const bf16x8* wp = reinterpret_cast<const bf16x8*>(wpk);

    for (int cb = 0; cb < CIBLKS; ++cb) {
        __syncthreads();
        {
            const bf16x8* wsrc = wp + (size_t)cb * 2304;
            bf16x8* wdst = reinterpret_cast<bf16x8*>(ws2);
            #pragma unroll
            for (int e = 0; e < 4; ++e)
                wdst[tid + e * 512] = wsrc[tid + e * 512];
            if (tid < 256) wdst[tid + 2048] = wsrc[tid + 2048];
        }
        #pragma unroll
        for (int tt = 0; tt < 2; ++tt) {
            int task = tid + tt * 512;
            if (task < 768) {
                int q8 = task / 192;
                int rr = (task % 192) >> 5;
                int xq = task & 31;
                int yy = y0 - 1 + rr;
                int x0 = xq * 4;
                int ci0 = cb * 32 + q8 * 8;
                u16x4 v[8];
                if (yy >= 0 && yy < 128) {
                    const unsigned short* sp;
                    if (ci0 < cinA) sp = srcA + ((size_t)b * cinA + ci0) * HW;
                    else            sp = srcB + ((size_t)b * cinB + (ci0 - cinA)) * HW;
                    sp += yy * 128 + x0;
                    #pragma unroll
                    for (int p = 0; p < 8; ++p)
                        v[p] = *reinterpret_cast<const u16x4*>(sp + p * HW);
                } else {
                    #pragma unroll
                    for (int p = 0; p < 8; ++p) v[p] = (u16x4)0;
                }
                #pragma unroll
                for (int i = 0; i < 4; ++i) {
                    int d = (i + xq) & 3;
                    int col = x0 + 1 + d;
                    int slot = q8 ^ ((col >> 2) & 3);
                    u16x8 o;
                    #pragma unroll
                    for (int p = 0; p < 8; ++p) o[p] = v[p][d];
                    *reinterpret_cast<u16x8*>(&xs[(rr * 133 + col) * 32 + slot * 8]) = o;
                }
            }
        }
        __syncthreads();
        __builtin_amdgcn_s_setprio(1);
        #pragma unroll
        for (int ky = 0; ky < 3; ++ky) {
            #pragma unroll
            for (int kx = 0; kx < 3; ++kx) {
                int kk = ky * 3 + kx;
                bf16x8 afr[4];
                #pragma unroll
                for (int ct = 0; ct < 4; ++ct)
                    afr[ct] = *reinterpret_cast<const bf16x8*>(&ws2[((kk * 4 + ct) * 64 + lane) * 8]);
                int row = wr + ky;
                bf16x8 bfr[4];
                #pragma unroll
                for (int nt = 0; nt < 4; ++nt) {
                    int col = wc * 64 + nt * 16 + l15 + kx;
                    int slot = qg ^ ((col >> 2) & 3);
                    bfr[nt] = *reinterpret_cast<const bf16x8*>(&xs[(row * 133 + col) * 32 + slot * 8]);
                }
                #pragma unroll
                for (int ct = 0; ct < 4; ++ct)
                    #pragma unroll
                    for (int nt = 0; nt < 4; ++nt)
                        acc[ct][nt] = __builtin_amdgcn_mfma_f32_16x16x32_bf16(afr[ct], bfr[nt], acc[ct][nt], 0, 0, 0);
            }
        }
        __builtin_amdgcn_s_setprio(0);
    }

    int row_out = y0 + wr;
    #pragma unroll
    for (int ct = 0; ct < 4; ++ct) {
        float4 bi = *reinterpret_cast<const float4*>(bias + ct * 16 + qg * 4);
        #pragma unroll
        for (int nt = 0; nt < 4; ++nt) {
            int col_out = wc * 64 + nt * 16 + l15;
            #pragma unroll
            for (int reg = 0; reg < 4; ++reg) {
                int co = ct * 16 + qg * 4 + reg;
                float bv = (reg == 0) ? bi.x : (reg == 1) ? bi.y : (reg == 2) ? bi.z : bi.w;
                float v = fmaxf(acc[ct][nt][reg] + bv, 0.f);
                size_t off = ((size_t)b * 64 + co) * HW + row_out * 128 + col_out;
                if (OBF16) ((unsigned short*)outp)[off] = f2bf(v);
                else       ((float*)outp)[off] = v;
            }
        }
    }
}

// ---------- launch ----------
extern "C" void kernel_launch(void* const* d_in, const int* in_sizes, int n_in,
                              void* d_out, int out_size, void* d_ws, size_t ws_size,
                              hipStream_t stream) {
    const float* x = (const float*)d_in[0];
    const float* y = (const float*)d_in[1];

    const float* qw[6]; const float* qs[6];
    QkvBias qb;
    for (int q = 0; q < 6; q++) {
        qw[q] = (const float*)d_in[2 + 3 * q];
        qs[q] = (const float*)d_in[3 + 3 * q];
        qb.b[q] = (const float*)d_in[4 + 3 * q];
    }
    const float* red_w = (const float*)d_in[20];
    const float* red_s = (const float*)d_in[21];
    const float* red_b = (const float*)d_in[22];
    const float* sec_w = (const float*)d_in[23];
    const float* sec_s = (const float*)d_in[24];
    const float* sec_b = (const float*)d_in[25];
    const float* g1 = (const float*)d_in[26];
    const float* g2 = (const float*)d_in[27];
    const float* g3 = (const float*)d_in[28];
    const float* g4 = (const float*)d_in[29];
    const float* sa_r_w = (const float*)d_in[30];
    const float* sa_i_w = (const float*)d_in[31];

    // ---- workspace layout ----
    float* WD = (float*)d_ws;                       // 512
    float* WU = WD + 512;                           // 512
    float* SIG = WU + 512;                          // 524288 (unused after fusion)
    float* MM = SIG + 524288;                       // 1048576 (unused after fusion)
    float* REF = MM + 1048576;                      // 4194304
    unsigned short* WPKR = (unsigned short*)(REF + 4194304);  // 147456
    unsigned short* WPKS = WPKR + 147456;           // 110592
    unsigned short* WPKQ = WPKS + 110592;           // 221184
    unsigned short* REB = WPKQ + 221184;            // 2097152
    unsigned short* QT  = REB + 2097152;            // 2097152  [2][16][1024][64]
    unsigned short* KT  = QT + 2097152;             // 2097152  [2][16][1024][64]
    unsigned short* VN  = KT + 2097152;             // 2097152  [2][16][64][1024]
    unsigned short* GATT = VN + 2097152;            // 16777216
    unsigned short* CAT4 = GATT + 16777216;         // 67108864
    // fragment buffers alias the CAT4 region (dead until k_up3)
    unsigned short* QTF = CAT4;                     // 2097152
    unsigned short* KTF = CAT4 + 2097152;           // 2097152
    unsigned short* VF  = CAT4 + 4194304;           // 3145728
    unsigned short* SECXY = CAT4;                   // alias (after red conv)

    k_init<<<1, 256, 0, stream>>>(WD, WU);
    k_down<<<2 * 16 * 64, 256, 0, stream>>>(x, y, WD, REB);
    for (int q = 0; q < 6; q++)
        k_wpack<<<18, 256, 0, stream>>>(qw[q], qs[q], WPKQ + (size_t)q * 36864, 64);
    k_wpackc<<<72, 256, 0, stream>>>(red_w, red_s, WPKR, 256);
    k_wpackc<<<54, 256, 0, stream>>>(sec_w, sec_s, WPKS, 192);
    k_qkv2<<<6 * 64, 256, 0, stream>>>(REB, WPKQ, qb, QT, KT, VN);
    k_packa<<<512, 256, 0, stream>>>(QT, KT, QTF, KTF);
    k_packv<<<128, 256, 0, stream>>>(VN, VF);
    k_attn3<<<4 * 16 * 64, 256, 0, stream>>>(QTF, KTF, VF, REF);
    k_up3<<<16 * 128, 256, 0, stream>>>(REF, WU, x, y, g1, g2, g3, g4, (__hip_bfloat16*)CAT4);
    k_conv<8, true><<<16 * 32, 512, 0, stream>>>(CAT4, 256, CAT4, WPKR, red_b, GATT);
    k_spa<<<2 * 16 * 8, 256, 0, stream>>>(x, y, sa_r_w, sa_i_w, SECXY);
    k_conv<6, false><<<16 * 32, 512, 0, stream>>>(GATT, 64, SECXY, WPKS, sec_b, d_out);
}